// Round 1
// baseline (1618.446 us; speedup 1.0000x reference)
//
#include <hip/hip_runtime.h>
#include <hip/hip_bf16.h>
#include <stdint.h>

#define M_DIM 8192
#define K_DIM 14336
#define N_DIM 4096
#define GROUP_SZ 128
#define BM 128
#define BN 128
#define BK 64

typedef short short8 __attribute__((ext_vector_type(8)));
typedef float f32x4 __attribute__((ext_vector_type(4)));

// fp32 -> bf16 raw bits, round-to-nearest-even
static __device__ __forceinline__ short f2bf(float f) {
  unsigned u = __builtin_bit_cast(unsigned, f);
  u += 0x7FFFu + ((u >> 16) & 1u);
  return (short)(u >> 16);
}

// async global->LDS, 16B per lane (dest = wave-uniform base + lane*16)
static __device__ __forceinline__ void gload_lds16(const void* g, void* lds) {
  __builtin_amdgcn_global_load_lds(
      (const __attribute__((address_space(1))) unsigned int*)g,
      (__attribute__((address_space(3))) unsigned int*)lds, 16, 0, 0);
}

// ---------------- pre-pass kernels (Tier 1 / Tier 2) ----------------

// qx fp32 [M,K] -> bf16 bits [M,K]
__global__ __launch_bounds__(256) void dp_convert_x(const float* __restrict__ x,
                                                    short* __restrict__ xb, int n8) {
  int stride = gridDim.x * 256;
  for (int i = blockIdx.x * 256 + threadIdx.x; i < n8; i += stride) {
    const float4* p = (const float4*)(x + (size_t)i * 8);
    float4 u0 = p[0], u1 = p[1];
    short8 v;
    v[0] = f2bf(u0.x); v[1] = f2bf(u0.y); v[2] = f2bf(u0.z); v[3] = f2bf(u0.w);
    v[4] = f2bf(u1.x); v[5] = f2bf(u1.y); v[6] = f2bf(u1.z); v[7] = f2bf(u1.w);
    *(short8*)(xb + (size_t)i * 8) = v;
  }
}

// W int4-packed [N, K/8] + group scales -> bf16 bits [N, K]
__global__ __launch_bounds__(256) void dp_dequant_w(const int* __restrict__ wq,
                                                    const float* __restrict__ wsc,
                                                    short* __restrict__ wb) {
  int p = blockIdx.x * 256 + threadIdx.x;  // 0..1791 (K/8)
  int n = blockIdx.y;
  int w = wq[(size_t)n * (K_DIM / 8) + p];
  float sc = wsc[(size_t)n * (K_DIM / GROUP_SZ) + (p >> 4)];
  short8 v;
#pragma unroll
  for (int j = 0; j < 8; ++j) {
    int q = (w << (28 - 4 * j)) >> 28;  // sign-extended nibble j (k = p*8+j)
    v[j] = f2bf((float)q * sc);
  }
  *(short8*)(wb + (size_t)n * K_DIM + (size_t)p * 8) = v;
}

// ---------------- GEMM ----------------
// AMODE: 0 = A from bf16 ws via global_load_lds, 1 = A from fp32 qx reg-staged
// BMODE: 0 = B from bf16 ws via global_load_lds, 1 = B from packed int4 reg-staged
template <int AMODE, int BMODE>
__global__ __launch_bounds__(256) void dp_gemm(
    const float* __restrict__ qx, const short* __restrict__ Xb,
    const int* __restrict__ Wq, const float* __restrict__ Wsc,
    const short* __restrict__ Wb, const float* __restrict__ qxscale,
    const float* __restrict__ residual, const float* __restrict__ bias,
    float* __restrict__ out) {
  __shared__ short As[BM * BK];  // [row m][k], k-contiguous, 16 KB
  __shared__ short Bs[BN * BK];  // [row n][k], 16 KB

  const int tid = threadIdx.x;
  const int lane = tid & 63;
  const int w = tid >> 6;

  // XCD-aware swizzle (nwg = 2048, divisible by 8 -> bijective)
  const int nwg = gridDim.x;
  const int cpx = nwg >> 3;
  const int wg = blockIdx.x;
  const int swz = (wg & 7) * cpx + (wg >> 3);
  const int bm = swz / (N_DIM / BN);
  const int bn = swz % (N_DIM / BN);
  const int m0 = bm * BM, n0 = bn * BN;

  const int wm = w >> 1, wn = w & 1;       // 2x2 waves -> 64x64 each
  const int lr = lane & 15, lg = lane >> 4;

  f32x4 acc[4][4];
#pragma unroll
  for (int i = 0; i < 4; ++i)
#pragma unroll
    for (int j = 0; j < 4; ++j) acc[i][j] = (f32x4){0.f, 0.f, 0.f, 0.f};

  for (int kt = 0; kt < K_DIM / BK; ++kt) {
    const int k0 = kt * BK;

    // ---- stage A tile [BM][BK] ----
    if (AMODE == 0) {
#pragma unroll
      for (int i = 0; i < 4; ++i) {
        int ldsb = i * 4096 + w * 1024 + lane * 16;  // linear byte offset
        int row = ldsb >> 7;                          // 128 B per row
        int ke = (ldsb & 127) >> 1;
        gload_lds16(Xb + (size_t)(m0 + row) * K_DIM + k0 + ke, (char*)As + ldsb);
      }
    } else {
#pragma unroll
      for (int i = 0; i < 4; ++i) {
        int ldsb = i * 4096 + tid * 16;
        int row = ldsb >> 7;
        int ke = (ldsb & 127) >> 1;
        const float4* p = (const float4*)(qx + (size_t)(m0 + row) * K_DIM + k0 + ke);
        float4 u0 = p[0], u1 = p[1];
        short8 v;
        v[0] = f2bf(u0.x); v[1] = f2bf(u0.y); v[2] = f2bf(u0.z); v[3] = f2bf(u0.w);
        v[4] = f2bf(u1.x); v[5] = f2bf(u1.y); v[6] = f2bf(u1.z); v[7] = f2bf(u1.w);
        *(short8*)((char*)As + ldsb) = v;
      }
    }

    // ---- stage B tile [BN][BK] ----
    if (BMODE == 0) {
#pragma unroll
      for (int i = 0; i < 4; ++i) {
        int ldsb = i * 4096 + w * 1024 + lane * 16;
        int row = ldsb >> 7;
        int ke = (ldsb & 127) >> 1;
        gload_lds16(Wb + (size_t)(n0 + row) * K_DIM + k0 + ke, (char*)Bs + ldsb);
      }
    } else {
      int row = tid >> 1;                 // 128 rows, 2 threads/row
      int kb = (tid & 1) * 32;            // 32 k per thread (one scale group slice)
      int4 pw = *(const int4*)(Wq + (size_t)(n0 + row) * (K_DIM / 8) + (k0 + kb) / 8);
      float sc = Wsc[(size_t)(n0 + row) * (K_DIM / GROUP_SZ) + (k0 + kb) / GROUP_SZ];
      int pv[4] = {pw.x, pw.y, pw.z, pw.w};
#pragma unroll
      for (int p = 0; p < 4; ++p) {
        short8 v;
#pragma unroll
        for (int j = 0; j < 8; ++j) {
          int q = (pv[p] << (28 - 4 * j)) >> 28;
          v[j] = f2bf((float)q * sc);
        }
        *(short8*)((char*)Bs + row * 128 + kb * 2 + p * 16) = v;
      }
    }

    __syncthreads();  // drains vmcnt (global_load_lds) + lgkmcnt (ds_write)

    // ---- compute: 2 k-subtiles x 4x4 fragments ----
#pragma unroll
    for (int s = 0; s < 2; ++s) {
      short8 a[4], b[4];
#pragma unroll
      for (int f = 0; f < 4; ++f)
        a[f] = *(const short8*)(&As[(wm * 64 + f * 16 + lr) * BK + s * 32 + lg * 8]);
#pragma unroll
      for (int f = 0; f < 4; ++f)
        b[f] = *(const short8*)(&Bs[(wn * 64 + f * 16 + lr) * BK + s * 32 + lg * 8]);
#pragma unroll
      for (int i = 0; i < 4; ++i)
#pragma unroll
        for (int j = 0; j < 4; ++j)
          acc[i][j] = __builtin_amdgcn_mfma_f32_16x16x32_bf16(a[i], b[j], acc[i][j], 0, 0, 0);
    }

    __syncthreads();  // protect LDS before next-tile overwrite
  }

  // ---- epilogue: y = acc*qxscale[m] + residual + bias[n] ----
  const int mb = m0 + wm * 64, nb = n0 + wn * 64;
#pragma unroll
  for (int i = 0; i < 4; ++i) {
#pragma unroll
    for (int j = 0; j < 4; ++j) {
      int n = nb + j * 16 + lr;
      float bv = bias[n];
#pragma unroll
      for (int r = 0; r < 4; ++r) {
        int m = mb + i * 16 + lg * 4 + r;  // C/D: col=lane&15, row=(lane>>4)*4+reg
        size_t off = (size_t)m * N_DIM + n;
        out[off] = acc[i][j][r] * qxscale[m] + residual[off] + bv;
      }
    }
  }
}

extern "C" void kernel_launch(void* const* d_in, const int* in_sizes, int n_in,
                              void* d_out, int out_size, void* d_ws, size_t ws_size,
                              hipStream_t stream) {
  const float* qx = (const float*)d_in[0];
  const float* qxscale = (const float*)d_in[1];
  const float* residual = (const float*)d_in[2];
  const int* wq = (const int*)d_in[3];
  const float* wsc = (const float*)d_in[4];
  const float* bias = (const float*)d_in[5];
  float* out = (float*)d_out;

  const size_t need_w = (size_t)N_DIM * K_DIM * 2;  // 117,440,512 B
  const size_t need_x = (size_t)M_DIM * K_DIM * 2;  // 234,881,024 B
  short* wb = (short*)d_ws;
  short* xb = (short*)((char*)d_ws + need_w);

  dim3 blk(256);
  dim3 gemm_grid((M_DIM / BM) * (N_DIM / BN));  // 2048

  if (ws_size >= need_w + need_x) {
    // Tier 1: both operands pre-converted to bf16 in ws
    dp_dequant_w<<<dim3(K_DIM / 8 / 256, N_DIM), blk, 0, stream>>>(wq, wsc, wb);
    dp_convert_x<<<dim3(2048), blk, 0, stream>>>(qx, xb, (int)((size_t)M_DIM * K_DIM / 8));
    dp_gemm<0, 0><<<gemm_grid, blk, 0, stream>>>(qx, xb, wq, wsc, wb, qxscale,
                                                 residual, bias, out);
  } else if (ws_size >= need_w) {
    // Tier 2: W pre-dequantized; A converted in-kernel
    dp_dequant_w<<<dim3(K_DIM / 8 / 256, N_DIM), blk, 0, stream>>>(wq, wsc, wb);
    dp_gemm<1, 0><<<gemm_grid, blk, 0, stream>>>(qx, nullptr, wq, wsc, wb, qxscale,
                                                 residual, bias, out);
  } else {
    // Tier 3: fully fused (no workspace)
    dp_gemm<1, 1><<<gemm_grid, blk, 0, stream>>>(qx, nullptr, wq, wsc, nullptr, qxscale,
                                                 residual, bias, out);
  }
}

// Round 2
// 1452.976 us; speedup vs baseline: 1.1139x; 1.1139x over previous
//
#include <hip/hip_runtime.h>
#include <hip/hip_bf16.h>
#include <stdint.h>

#define M_DIM 8192
#define K_DIM 14336
#define N_DIM 4096
#define GROUP_SZ 128
#define BM 128
#define BN 128
#define BK 64

typedef short short8 __attribute__((ext_vector_type(8)));
typedef float f32x4 __attribute__((ext_vector_type(4)));

// fp32 -> bf16 raw bits, round-to-nearest-even
static __device__ __forceinline__ short f2bf(float f) {
  unsigned u = __builtin_bit_cast(unsigned, f);
  u += 0x7FFFu + ((u >> 16) & 1u);
  return (short)(u >> 16);
}

// async global->LDS, 16B per lane (dest = wave-uniform base + lane*16)
static __device__ __forceinline__ void gload_lds16(const void* g, void* lds) {
  __builtin_amdgcn_global_load_lds(
      (const __attribute__((address_space(1))) unsigned int*)g,
      (__attribute__((address_space(3))) unsigned int*)lds, 16, 0, 0);
}

// ---------------- pre-pass kernels (Tier 1 / Tier 2) ----------------

// qx fp32 [M,K] -> bf16 bits [M,K]
__global__ __launch_bounds__(256) void dp_convert_x(const float* __restrict__ x,
                                                    short* __restrict__ xb, int n8) {
  int stride = gridDim.x * 256;
  for (int i = blockIdx.x * 256 + threadIdx.x; i < n8; i += stride) {
    const float4* p = (const float4*)(x + (size_t)i * 8);
    float4 u0 = p[0], u1 = p[1];
    short8 v;
    v[0] = f2bf(u0.x); v[1] = f2bf(u0.y); v[2] = f2bf(u0.z); v[3] = f2bf(u0.w);
    v[4] = f2bf(u1.x); v[5] = f2bf(u1.y); v[6] = f2bf(u1.z); v[7] = f2bf(u1.w);
    *(short8*)(xb + (size_t)i * 8) = v;
  }
}

// W int4-packed [N, K/8] + group scales -> bf16 bits [N, K]
__global__ __launch_bounds__(256) void dp_dequant_w(const int* __restrict__ wq,
                                                    const float* __restrict__ wsc,
                                                    short* __restrict__ wb) {
  int p = blockIdx.x * 256 + threadIdx.x;  // 0..1791 (K/8)
  int n = blockIdx.y;
  int w = wq[(size_t)n * (K_DIM / 8) + p];
  float sc = wsc[(size_t)n * (K_DIM / GROUP_SZ) + (p >> 4)];
  short8 v;
#pragma unroll
  for (int j = 0; j < 8; ++j) {
    int q = (w << (28 - 4 * j)) >> 28;  // sign-extended nibble j (k = p*8+j)
    v[j] = f2bf((float)q * sc);
  }
  *(short8*)(wb + (size_t)n * K_DIM + (size_t)p * 8) = v;
}

// ---------------- GEMM ----------------
// LDS tile layout: [row][8 slots of 16B], physical slot = logical slot ^ (row&7).
// global_load_lds writes LDS linearly (wave-uniform base + lane*16), so the
// swizzle is applied on the per-lane GLOBAL source address (rule #21), and the
// identical XOR is applied on the ds_read fragment address. Post-swizzle the
// 16 lanes of a fragment read spread over 8 bank-quads (2-way = free, m136).
//
// AMODE: 0 = A from bf16 ws via global_load_lds, 1 = A from fp32 qx reg-staged
// BMODE: 0 = B from bf16 ws via global_load_lds, 1 = B from packed int4 reg-staged
template <int AMODE, int BMODE>
__global__ __launch_bounds__(256) void dp_gemm(
    const float* __restrict__ qx, const short* __restrict__ Xb,
    const int* __restrict__ Wq, const float* __restrict__ Wsc,
    const short* __restrict__ Wb, const float* __restrict__ qxscale,
    const float* __restrict__ residual, const float* __restrict__ bias,
    float* __restrict__ out) {
  __shared__ short As[BM * BK];  // 16 KB, swizzled slots
  __shared__ short Bs[BN * BK];  // 16 KB, swizzled slots

  const int tid = threadIdx.x;
  const int lane = tid & 63;
  const int w = tid >> 6;

  // XCD-aware swizzle (nwg = 2048, divisible by 8 -> bijective)
  const int nwg = gridDim.x;
  const int cpx = nwg >> 3;
  const int wg = blockIdx.x;
  const int swz = (wg & 7) * cpx + (wg >> 3);
  const int bm = swz / (N_DIM / BN);
  const int bn = swz % (N_DIM / BN);
  const int m0 = bm * BM, n0 = bn * BN;

  const int wm = w >> 1, wn = w & 1;       // 2x2 waves -> 64x64 each
  const int lr = lane & 15, lg = lane >> 4;

  f32x4 acc[4][4];
#pragma unroll
  for (int i = 0; i < 4; ++i)
#pragma unroll
    for (int j = 0; j < 4; ++j) acc[i][j] = (f32x4){0.f, 0.f, 0.f, 0.f};

  for (int kt = 0; kt < K_DIM / BK; ++kt) {
    const int k0 = kt * BK;

    // ---- stage A tile [BM][BK] ----
    if (AMODE == 0) {
#pragma unroll
      for (int i = 0; i < 4; ++i) {
        int ldsb = i * 4096 + w * 1024 + lane * 16;   // linear LDS byte offset
        int row = ldsb >> 7;                           // 128 B per row
        int slog = ((ldsb >> 4) & 7) ^ (row & 7);      // pre-swizzled source slot
        gload_lds16(Xb + (size_t)(m0 + row) * K_DIM + k0 + slog * 8, (char*)As + ldsb);
      }
    } else {
#pragma unroll
      for (int i = 0; i < 4; ++i) {
        int ldsb = i * 4096 + tid * 16;
        int row = ldsb >> 7;
        int slog = ((ldsb >> 4) & 7) ^ (row & 7);
        const float4* p = (const float4*)(qx + (size_t)(m0 + row) * K_DIM + k0 + slog * 8);
        float4 u0 = p[0], u1 = p[1];
        short8 v;
        v[0] = f2bf(u0.x); v[1] = f2bf(u0.y); v[2] = f2bf(u0.z); v[3] = f2bf(u0.w);
        v[4] = f2bf(u1.x); v[5] = f2bf(u1.y); v[6] = f2bf(u1.z); v[7] = f2bf(u1.w);
        *(short8*)((char*)As + ldsb) = v;  // phys slot stays linear
      }
    }

    // ---- stage B tile [BN][BK] ----
    if (BMODE == 0) {
#pragma unroll
      for (int i = 0; i < 4; ++i) {
        int ldsb = i * 4096 + w * 1024 + lane * 16;
        int row = ldsb >> 7;
        int slog = ((ldsb >> 4) & 7) ^ (row & 7);
        gload_lds16(Wb + (size_t)(n0 + row) * K_DIM + k0 + slog * 8, (char*)Bs + ldsb);
      }
    } else {
      int row = tid >> 1;                 // 128 rows, 2 threads/row
      int kb = (tid & 1) * 32;            // 32 k per thread (one scale group slice)
      int4 pw = *(const int4*)(Wq + (size_t)(n0 + row) * (K_DIM / 8) + (k0 + kb) / 8);
      float sc = Wsc[(size_t)(n0 + row) * (K_DIM / GROUP_SZ) + (k0 + kb) / GROUP_SZ];
      int pv[4] = {pw.x, pw.y, pw.z, pw.w};
#pragma unroll
      for (int p = 0; p < 4; ++p) {
        short8 v;
#pragma unroll
        for (int j = 0; j < 8; ++j) {
          int q = (pv[p] << (28 - 4 * j)) >> 28;
          v[j] = f2bf((float)q * sc);
        }
        int slog = (tid & 1) * 4 + p;
        int sp = slog ^ (row & 7);
        *(short8*)((char*)Bs + row * 128 + sp * 16) = v;
      }
    }

    __syncthreads();  // drains vmcnt (global_load_lds) + lgkmcnt (ds_write)

    // ---- compute: 2 k-subtiles x 4x4 fragments ----
#pragma unroll
    for (int s = 0; s < 2; ++s) {
      short8 a[4], b[4];
#pragma unroll
      for (int f = 0; f < 4; ++f) {
        int row = wm * 64 + f * 16 + lr;
        int sp = (s * 4 + lg) ^ (row & 7);            // swizzled read slot
        a[f] = *(const short8*)((char*)As + row * 128 + sp * 16);
      }
#pragma unroll
      for (int f = 0; f < 4; ++f) {
        int row = wn * 64 + f * 16 + lr;
        int sp = (s * 4 + lg) ^ (row & 7);
        b[f] = *(const short8*)((char*)Bs + row * 128 + sp * 16);
      }
#pragma unroll
      for (int i = 0; i < 4; ++i)
#pragma unroll
        for (int j = 0; j < 4; ++j)
          acc[i][j] = __builtin_amdgcn_mfma_f32_16x16x32_bf16(a[i], b[j], acc[i][j], 0, 0, 0);
    }

    __syncthreads();  // protect LDS before next-tile overwrite
  }

  // ---- epilogue: y = acc*qxscale[m] + residual + bias[n] ----
  const int mb = m0 + wm * 64, nb = n0 + wn * 64;
#pragma unroll
  for (int i = 0; i < 4; ++i) {
#pragma unroll
    for (int j = 0; j < 4; ++j) {
      int n = nb + j * 16 + lr;
      float bv = bias[n];
#pragma unroll
      for (int r = 0; r < 4; ++r) {
        int m = mb + i * 16 + lg * 4 + r;  // C/D: col=lane&15, row=(lane>>4)*4+reg
        size_t off = (size_t)m * N_DIM + n;
        out[off] = acc[i][j][r] * qxscale[m] + residual[off] + bv;
      }
    }
  }
}

extern "C" void kernel_launch(void* const* d_in, const int* in_sizes, int n_in,
                              void* d_out, int out_size, void* d_ws, size_t ws_size,
                              hipStream_t stream) {
  const float* qx = (const float*)d_in[0];
  const float* qxscale = (const float*)d_in[1];
  const float* residual = (const float*)d_in[2];
  const int* wq = (const int*)d_in[3];
  const float* wsc = (const float*)d_in[4];
  const float* bias = (const float*)d_in[5];
  float* out = (float*)d_out;

  const size_t need_w = (size_t)N_DIM * K_DIM * 2;  // 117,440,512 B
  const size_t need_x = (size_t)M_DIM * K_DIM * 2;  // 234,881,024 B
  short* wb = (short*)d_ws;
  short* xb = (short*)((char*)d_ws + need_w);

  dim3 blk(256);
  dim3 gemm_grid((M_DIM / BM) * (N_DIM / BN));  // 2048

  if (ws_size >= need_w + need_x) {
    // Tier 1: both operands pre-converted to bf16 in ws
    dp_dequant_w<<<dim3(K_DIM / 8 / 256, N_DIM), blk, 0, stream>>>(wq, wsc, wb);
    dp_convert_x<<<dim3(2048), blk, 0, stream>>>(qx, xb, (int)((size_t)M_DIM * K_DIM / 8));
    dp_gemm<0, 0><<<gemm_grid, blk, 0, stream>>>(qx, xb, wq, wsc, wb, qxscale,
                                                 residual, bias, out);
  } else if (ws_size >= need_w) {
    // Tier 2: W pre-dequantized; A converted in-kernel
    dp_dequant_w<<<dim3(K_DIM / 8 / 256, N_DIM), blk, 0, stream>>>(wq, wsc, wb);
    dp_gemm<1, 0><<<gemm_grid, blk, 0, stream>>>(qx, nullptr, wq, wsc, wb, qxscale,
                                                 residual, bias, out);
  } else {
    // Tier 3: fully fused (no workspace)
    dp_gemm<1, 1><<<gemm_grid, blk, 0, stream>>>(qx, nullptr, wq, wsc, nullptr, qxscale,
                                                 residual, bias, out);
  }
}

// Round 3
// 887.639 us; speedup vs baseline: 1.8233x; 1.6369x over previous
//
#include <hip/hip_runtime.h>
#include <hip/hip_bf16.h>
#include <stdint.h>

#define M_DIM 8192
#define K_DIM 14336
#define N_DIM 4096
#define GROUP_SZ 128

typedef short short8 __attribute__((ext_vector_type(8)));
typedef float f32x4 __attribute__((ext_vector_type(4)));

// fp32 -> bf16 raw bits, round-to-nearest-even
static __device__ __forceinline__ short f2bf(float f) {
  unsigned u = __builtin_bit_cast(unsigned, f);
  u += 0x7FFFu + ((u >> 16) & 1u);
  return (short)(u >> 16);
}

// async global->LDS, 16B per lane (dest = wave-uniform base + lane*16)
static __device__ __forceinline__ void gload_lds16(const void* g, void* lds) {
  __builtin_amdgcn_global_load_lds(
      (const __attribute__((address_space(1))) unsigned int*)g,
      (__attribute__((address_space(3))) unsigned int*)lds, 16, 0, 0);
}

// ---------------- pre-pass kernels ----------------

__global__ __launch_bounds__(256) void dp_convert_x(const float* __restrict__ x,
                                                    short* __restrict__ xb, int n8) {
  int stride = gridDim.x * 256;
  for (int i = blockIdx.x * 256 + threadIdx.x; i < n8; i += stride) {
    const float4* p = (const float4*)(x + (size_t)i * 8);
    float4 u0 = p[0], u1 = p[1];
    short8 v;
    v[0] = f2bf(u0.x); v[1] = f2bf(u0.y); v[2] = f2bf(u0.z); v[3] = f2bf(u0.w);
    v[4] = f2bf(u1.x); v[5] = f2bf(u1.y); v[6] = f2bf(u1.z); v[7] = f2bf(u1.w);
    *(short8*)(xb + (size_t)i * 8) = v;
  }
}

__global__ __launch_bounds__(256) void dp_dequant_w(const int* __restrict__ wq,
                                                    const float* __restrict__ wsc,
                                                    short* __restrict__ wb) {
  int p = blockIdx.x * 256 + threadIdx.x;  // 0..1791 (K/8)
  int n = blockIdx.y;
  int w = wq[(size_t)n * (K_DIM / 8) + p];
  float sc = wsc[(size_t)n * (K_DIM / GROUP_SZ) + (p >> 4)];
  short8 v;
#pragma unroll
  for (int j = 0; j < 8; ++j) {
    int q = (w << (28 - 4 * j)) >> 28;
    v[j] = f2bf((float)q * sc);
  }
  *(short8*)(wb + (size_t)n * K_DIM + (size_t)p * 8) = v;
}

// ---------------- Tier-1 GEMM: 256x256 tile, 8-phase schedule ----------------
// LDS 128KB: A slots (buf,half) at (buf*2+half)*16384; B at +65536.
// Half = 128 rows x 64 k bf16, rows of 8x16B slots, phys_slot = log_slot ^ (row&7)
// (linear gload_lds dest + pre-swizzled global source + swizzled ds_read).
// Stage schedule: each slot re-staged one full phase after its last read;
// counted vmcnt(4) at phases 4/8 only (2 half-tiles in flight).
__global__ __launch_bounds__(512, 2) void dp_gemm8(
    const short* __restrict__ Xb, const short* __restrict__ Wb,
    const float* __restrict__ qxscale, const float* __restrict__ residual,
    const float* __restrict__ bias, float* __restrict__ out) {
  __shared__ __align__(16) char lds[131072];

  const int tid = threadIdx.x;
  const int lane = tid & 63;
  const int wid = tid >> 6;
  const int wm = wid >> 2, wn = wid & 3;   // 2 x 4 waves
  const int lr = lane & 15, lg = lane >> 4;

  // XCD-bijective swizzle (nwg = 512, 512 % 8 == 0)
  const int wg = blockIdx.x;
  const int swz = (wg & 7) * 64 + (wg >> 3);
  const int m0 = (swz >> 4) * 256;  // 32 m-tiles
  const int n0 = (swz & 15) * 256;  // 16 n-tiles

  // fragment ds byte-offsets within a half-buffer (constant per thread)
  int offA[4][2], offB[2][2];
#pragma unroll
  for (int mf = 0; mf < 4; ++mf) {
    int r = wm * 64 + mf * 16 + lr;  // 0..127
#pragma unroll
    for (int s = 0; s < 2; ++s)
      offA[mf][s] = r * 128 + (((s * 4 + lg) ^ (r & 7)) << 4);
  }
#pragma unroll
  for (int nf = 0; nf < 2; ++nf) {
    int r = wn * 32 + nf * 16 + lr;  // 0..127
#pragma unroll
    for (int s = 0; s < 2; ++s)
      offB[nf][s] = r * 128 + (((s * 4 + lg) ^ (r & 7)) << 4);
  }

  // staging constants: 2 gload_lds per thread per half-tile, linear LDS dest,
  // inverse-swizzled global k offset
  const int srow = tid >> 3;                       // 0..63
  const int ksrc = ((tid & 7) ^ (srow & 7)) * 8;   // pre-swizzled k elem
  const size_t aRow = (size_t)(m0 + srow) * K_DIM + ksrc;
  const size_t bRow = (size_t)(n0 + srow) * K_DIM + ksrc;
  const int dst0 = tid * 16;

  f32x4 acc[8][4];
#pragma unroll
  for (int i = 0; i < 8; ++i)
#pragma unroll
    for (int j = 0; j < 4; ++j) acc[i][j] = (f32x4){0.f, 0.f, 0.f, 0.f};

  short8 aF[4][2];      // A frags for current mh (reloaded at mh change)
  short8 bF[2][2][2];   // B frags [nh][nf][s], resident for whole K-tile

#define STAGE_A(kt, h)                                                         \
  do {                                                                         \
    size_t g_ = aRow + (size_t)((h) * 128) * K_DIM + (size_t)(kt) * 64;        \
    int d_ = ((((kt) & 1) * 2 + (h)) << 14) + dst0;                            \
    gload_lds16(Xb + g_, lds + d_);                                            \
    gload_lds16(Xb + g_ + (size_t)64 * K_DIM, lds + d_ + 8192);                \
  } while (0)

#define STAGE_B(kt, h)                                                         \
  do {                                                                         \
    size_t g_ = bRow + (size_t)((h) * 128) * K_DIM + (size_t)(kt) * 64;        \
    int d_ = 65536 + ((((kt) & 1) * 2 + (h)) << 14) + dst0;                    \
    gload_lds16(Wb + g_, lds + d_);                                            \
    gload_lds16(Wb + g_ + (size_t)64 * K_DIM, lds + d_ + 8192);                \
  } while (0)

#define FENCE asm volatile("" ::: "memory")

  // PHASE: optional A/B fragment loads, stage stmt, counted-wait stmt,
  // barrier, MFMA cluster under setprio, barrier.
#define PHASE(kt, mh, nh, LA, LB, STMT, WMT)                                   \
  do {                                                                         \
    if (LA) {                                                                  \
      const char* Ab_ = lds + ((((kt) & 1) * 2 + (mh)) << 14);                 \
      _Pragma("unroll") for (int mf = 0; mf < 4; ++mf)                         \
          _Pragma("unroll") for (int s = 0; s < 2; ++s)                        \
              aF[mf][s] = *(const short8*)(Ab_ + offA[mf][s]);                 \
    }                                                                          \
    if (LB) {                                                                  \
      const char* Bb_ = lds + 65536 + ((((kt) & 1) * 2 + (nh)) << 14);         \
      _Pragma("unroll") for (int nf = 0; nf < 2; ++nf)                         \
          _Pragma("unroll") for (int s = 0; s < 2; ++s)                        \
              bF[nh][nf][s] = *(const short8*)(Bb_ + offB[nf][s]);             \
    }                                                                          \
    STMT;                                                                      \
    FENCE;                                                                     \
    WMT;                                                                       \
    __builtin_amdgcn_s_barrier();                                              \
    FENCE;                                                                     \
    __builtin_amdgcn_s_setprio(1);                                             \
    _Pragma("unroll") for (int mf = 0; mf < 4; ++mf)                           \
        _Pragma("unroll") for (int nf = 0; nf < 2; ++nf)                       \
            _Pragma("unroll") for (int s = 0; s < 2; ++s)                      \
                acc[(mh) * 4 + mf][(nh) * 2 + nf] =                            \
                    __builtin_amdgcn_mfma_f32_16x16x32_bf16(                   \
                        aF[mf][s], bF[nh][nf][s],                              \
                        acc[(mh) * 4 + mf][(nh) * 2 + nf], 0, 0, 0);           \
    __builtin_amdgcn_s_setprio(0);                                             \
    FENCE;                                                                     \
    __builtin_amdgcn_s_barrier();                                              \
    FENCE;                                                                     \
  } while (0)

  // ---- prologue: stage kt0 fully + kt1 halves A0,B0; wait kt0 landed ----
  STAGE_A(0, 0); STAGE_B(0, 0); STAGE_A(0, 1); STAGE_B(0, 1);
  STAGE_A(1, 0); STAGE_B(1, 0);
  FENCE;
  asm volatile("s_waitcnt vmcnt(4)" ::: "memory");
  __builtin_amdgcn_s_barrier();
  FENCE;

  // ---- main loop: 112 iterations x 2 K-tiles (K/64 = 224) ----
  for (int i = 0; i < 112; ++i) {
    const int t = 2 * i;
    const bool st = (i < 111);
    PHASE(t, 0, 0, 1, 1, { STAGE_A(t + 1, 1); }, {});
    PHASE(t, 0, 1, 0, 1, { STAGE_B(t + 1, 1); }, {});
    PHASE(t, 1, 0, 1, 0, { if (st) STAGE_A(t + 2, 0); }, {});
    PHASE(t, 1, 1, 0, 0, { if (st) STAGE_B(t + 2, 0); },
          {
            if (st) asm volatile("s_waitcnt vmcnt(4)" ::: "memory");
            else    asm volatile("s_waitcnt vmcnt(0)" ::: "memory");
          });
    PHASE(t + 1, 0, 0, 1, 1, { if (st) STAGE_A(t + 2, 1); }, {});
    PHASE(t + 1, 0, 1, 0, 1, { if (st) STAGE_B(t + 2, 1); }, {});
    PHASE(t + 1, 1, 0, 1, 0, { if (st) STAGE_A(t + 3, 0); }, {});
    PHASE(t + 1, 1, 1, 0, 0, { if (st) STAGE_B(t + 3, 0); },
          {
            if (st) asm volatile("s_waitcnt vmcnt(4)" ::: "memory");
            else    asm volatile("s_waitcnt vmcnt(0)" ::: "memory");
          });
  }

  // ---- epilogue: y = acc*qxscale[m] + residual + bias[n] ----
#pragma unroll
  for (int mh = 0; mh < 2; ++mh)
#pragma unroll
    for (int mf = 0; mf < 4; ++mf)
#pragma unroll
      for (int nh = 0; nh < 2; ++nh)
#pragma unroll
        for (int nf = 0; nf < 2; ++nf) {
          int n = n0 + wn * 32 + nh * 128 + nf * 16 + lr;
          float bv = bias[n];
          f32x4 v = acc[mh * 4 + mf][nh * 2 + nf];
#pragma unroll
          for (int rr = 0; rr < 4; ++rr) {
            int m = m0 + wm * 64 + mh * 128 + mf * 16 + lg * 4 + rr;
            size_t off = (size_t)m * N_DIM + n;
            out[off] = v[rr] * qxscale[m] + residual[off] + bv;
          }
        }
#undef PHASE
#undef STAGE_A
#undef STAGE_B
#undef FENCE
}

// ---------------- fallback GEMM (tiers 2/3): 128x128, 2-barrier ----------------
template <int AMODE, int BMODE>
__global__ __launch_bounds__(256) void dp_gemm(
    const float* __restrict__ qx, const short* __restrict__ Xb,
    const int* __restrict__ Wq, const float* __restrict__ Wsc,
    const short* __restrict__ Wb, const float* __restrict__ qxscale,
    const float* __restrict__ residual, const float* __restrict__ bias,
    float* __restrict__ out) {
  __shared__ short As[128 * 64];
  __shared__ short Bs[128 * 64];

  const int tid = threadIdx.x;
  const int lane = tid & 63;
  const int w = tid >> 6;

  const int nwg = gridDim.x;
  const int cpx = nwg >> 3;
  const int wg = blockIdx.x;
  const int swz = (wg & 7) * cpx + (wg >> 3);
  const int bm = swz / (N_DIM / 128);
  const int bn = swz % (N_DIM / 128);
  const int m0 = bm * 128, n0 = bn * 128;

  const int wm = w >> 1, wn = w & 1;
  const int lr = lane & 15, lg = lane >> 4;

  f32x4 acc[4][4];
#pragma unroll
  for (int i = 0; i < 4; ++i)
#pragma unroll
    for (int j = 0; j < 4; ++j) acc[i][j] = (f32x4){0.f, 0.f, 0.f, 0.f};

  for (int kt = 0; kt < K_DIM / 64; ++kt) {
    const int k0 = kt * 64;
#pragma unroll
    for (int i = 0; i < 4; ++i) {
      int ldsb = i * 4096 + tid * 16;
      int row = ldsb >> 7;
      int slog = ((ldsb >> 4) & 7) ^ (row & 7);
      const float4* p = (const float4*)(qx + (size_t)(m0 + row) * K_DIM + k0 + slog * 8);
      float4 u0 = p[0], u1 = p[1];
      short8 v;
      v[0] = f2bf(u0.x); v[1] = f2bf(u0.y); v[2] = f2bf(u0.z); v[3] = f2bf(u0.w);
      v[4] = f2bf(u1.x); v[5] = f2bf(u1.y); v[6] = f2bf(u1.z); v[7] = f2bf(u1.w);
      *(short8*)((char*)As + ldsb) = v;
    }
    if (BMODE == 0) {
#pragma unroll
      for (int i = 0; i < 4; ++i) {
        int ldsb = i * 4096 + w * 1024 + lane * 16;
        int row = ldsb >> 7;
        int slog = ((ldsb >> 4) & 7) ^ (row & 7);
        gload_lds16(Wb + (size_t)(n0 + row) * K_DIM + k0 + slog * 8, (char*)Bs + ldsb);
      }
    } else {
      int row = tid >> 1;
      int kb = (tid & 1) * 32;
      int4 pw = *(const int4*)(Wq + (size_t)(n0 + row) * (K_DIM / 8) + (k0 + kb) / 8);
      float sc = Wsc[(size_t)(n0 + row) * (K_DIM / GROUP_SZ) + (k0 + kb) / GROUP_SZ];
      int pv[4] = {pw.x, pw.y, pw.z, pw.w};
#pragma unroll
      for (int p = 0; p < 4; ++p) {
        short8 v;
#pragma unroll
        for (int j = 0; j < 8; ++j) {
          int q = (pv[p] << (28 - 4 * j)) >> 28;
          v[j] = f2bf((float)q * sc);
        }
        int slog = (tid & 1) * 4 + p;
        int sp = slog ^ (row & 7);
        *(short8*)((char*)Bs + row * 128 + sp * 16) = v;
      }
    }
    __syncthreads();
#pragma unroll
    for (int s = 0; s < 2; ++s) {
      short8 a[4], b[4];
#pragma unroll
      for (int f = 0; f < 4; ++f) {
        int row = wm * 64 + f * 16 + lr;
        int sp = (s * 4 + lg) ^ (row & 7);
        a[f] = *(const short8*)((char*)As + row * 128 + sp * 16);
      }
#pragma unroll
      for (int f = 0; f < 4; ++f) {
        int row = wn * 64 + f * 16 + lr;
        int sp = (s * 4 + lg) ^ (row & 7);
        b[f] = *(const short8*)((char*)Bs + row * 128 + sp * 16);
      }
#pragma unroll
      for (int i = 0; i < 4; ++i)
#pragma unroll
        for (int j = 0; j < 4; ++j)
          acc[i][j] = __builtin_amdgcn_mfma_f32_16x16x32_bf16(a[i], b[j], acc[i][j], 0, 0, 0);
    }
    __syncthreads();
  }

  const int mb = m0 + wm * 64, nb = n0 + wn * 64;
#pragma unroll
  for (int i = 0; i < 4; ++i)
#pragma unroll
    for (int j = 0; j < 4; ++j) {
      int n = nb + j * 16 + lr;
      float bv = bias[n];
#pragma unroll
      for (int r = 0; r < 4; ++r) {
        int m = mb + i * 16 + lg * 4 + r;
        size_t off = (size_t)m * N_DIM + n;
        out[off] = acc[i][j][r] * qxscale[m] + residual[off] + bv;
      }
    }
}

extern "C" void kernel_launch(void* const* d_in, const int* in_sizes, int n_in,
                              void* d_out, int out_size, void* d_ws, size_t ws_size,
                              hipStream_t stream) {
  const float* qx = (const float*)d_in[0];
  const float* qxscale = (const float*)d_in[1];
  const float* residual = (const float*)d_in[2];
  const int* wq = (const int*)d_in[3];
  const float* wsc = (const float*)d_in[4];
  const float* bias = (const float*)d_in[5];
  float* out = (float*)d_out;

  const size_t need_w = (size_t)N_DIM * K_DIM * 2;
  const size_t need_x = (size_t)M_DIM * K_DIM * 2;
  short* wb = (short*)d_ws;
  short* xb = (short*)((char*)d_ws + need_w);

  if (ws_size >= need_w + need_x) {
    dp_dequant_w<<<dim3(K_DIM / 8 / 256, N_DIM), dim3(256), 0, stream>>>(wq, wsc, wb);
    dp_convert_x<<<dim3(2048), dim3(256), 0, stream>>>(qx, xb,
                                                       (int)((size_t)M_DIM * K_DIM / 8));
    dp_gemm8<<<dim3((M_DIM / 256) * (N_DIM / 256)), dim3(512), 0, stream>>>(
        xb, wb, qxscale, residual, bias, out);
  } else if (ws_size >= need_w) {
    dp_dequant_w<<<dim3(K_DIM / 8 / 256, N_DIM), dim3(256), 0, stream>>>(wq, wsc, wb);
    dp_gemm<1, 0><<<dim3(2048), dim3(256), 0, stream>>>(qx, nullptr, wq, wsc, wb,
                                                        qxscale, residual, bias, out);
  } else {
    dp_gemm<1, 1><<<dim3(2048), dim3(256), 0, stream>>>(qx, nullptr, wq, wsc, nullptr,
                                                        qxscale, residual, bias, out);
  }
}

// Round 4
// 848.999 us; speedup vs baseline: 1.9063x; 1.0455x over previous
//
#include <hip/hip_runtime.h>
#include <hip/hip_bf16.h>
#include <stdint.h>

#define M_DIM 8192
#define K_DIM 14336
#define N_DIM 4096
#define GROUP_SZ 128

typedef short short8 __attribute__((ext_vector_type(8)));
typedef float f32x4 __attribute__((ext_vector_type(4)));

// fp32 -> bf16 raw bits, round-to-nearest-even
static __device__ __forceinline__ short f2bf(float f) {
  unsigned u = __builtin_bit_cast(unsigned, f);
  u += 0x7FFFu + ((u >> 16) & 1u);
  return (short)(u >> 16);
}

// async global->LDS, 16B per lane (dest = wave-uniform base + lane*16)
static __device__ __forceinline__ void gload_lds16(const void* g, void* lds) {
  __builtin_amdgcn_global_load_lds(
      (const __attribute__((address_space(1))) unsigned int*)g,
      (__attribute__((address_space(3))) unsigned int*)lds, 16, 0, 0);
}

// ---------------- pre-pass kernels ----------------

__global__ __launch_bounds__(256) void dp_convert_x(const float* __restrict__ x,
                                                    short* __restrict__ xb, int n8) {
  int stride = gridDim.x * 256;
  for (int i = blockIdx.x * 256 + threadIdx.x; i < n8; i += stride) {
    const float4* p = (const float4*)(x + (size_t)i * 8);
    float4 u0 = p[0], u1 = p[1];
    short8 v;
    v[0] = f2bf(u0.x); v[1] = f2bf(u0.y); v[2] = f2bf(u0.z); v[3] = f2bf(u0.w);
    v[4] = f2bf(u1.x); v[5] = f2bf(u1.y); v[6] = f2bf(u1.z); v[7] = f2bf(u1.w);
    *(short8*)(xb + (size_t)i * 8) = v;
  }
}

__global__ __launch_bounds__(256) void dp_dequant_w(const int* __restrict__ wq,
                                                    const float* __restrict__ wsc,
                                                    short* __restrict__ wb) {
  int p = blockIdx.x * 256 + threadIdx.x;  // 0..1791 (K/8)
  int n = blockIdx.y;
  int w = wq[(size_t)n * (K_DIM / 8) + p];
  float sc = wsc[(size_t)n * (K_DIM / GROUP_SZ) + (p >> 4)];
  short8 v;
#pragma unroll
  for (int j = 0; j < 8; ++j) {
    int q = (w << (28 - 4 * j)) >> 28;
    v[j] = f2bf((float)q * sc);
  }
  *(short8*)(wb + (size_t)n * K_DIM + (size_t)p * 8) = v;
}

// ---------------- Tier-1 GEMM: 256x256 tile, 8-phase, single barrier/phase ----
// LDS 128KB: A slots (buf,half) at (buf*2+half)*16384; B at +65536.
// Half = 128 rows x 64 k bf16, rows of 8x16B slots, phys_slot = log_slot ^ (row&7)
// (linear gload_lds dest + pre-swizzled global source + swizzled ds_read).
// Stage schedule: every stage targets a slot last-read >=2 barriers earlier;
// reads of a slot are covered by the per-wave vmcnt(4)+barrier at phases 4/8.
// One barrier per phase (pre-MFMA) lets waves desync across phase boundaries.
__global__ __launch_bounds__(512, 2) void dp_gemm8(
    const short* __restrict__ Xb, const short* __restrict__ Wb,
    const float* __restrict__ qxscale, const float* __restrict__ residual,
    const float* __restrict__ bias, float* __restrict__ out) {
  __shared__ __align__(16) char lds[131072];

  const int tid = threadIdx.x;
  const int lane = tid & 63;
  const int wid = tid >> 6;
  const int wm = wid >> 2, wn = wid & 3;   // 2 x 4 waves
  const int lr = lane & 15, lg = lane >> 4;

  // XCD-bijective swizzle (nwg = 512, 512 % 8 == 0)
  const int wg = blockIdx.x;
  const int swz = (wg & 7) * 64 + (wg >> 3);
  const int m0 = (swz >> 4) * 256;  // 32 m-tiles
  const int n0 = (swz & 15) * 256;  // 16 n-tiles

  // fragment ds byte-offsets within a half-buffer (constant per thread)
  int offA[4][2], offB[2][2];
#pragma unroll
  for (int mf = 0; mf < 4; ++mf) {
    int r = wm * 64 + mf * 16 + lr;  // 0..127
#pragma unroll
    for (int s = 0; s < 2; ++s)
      offA[mf][s] = r * 128 + (((s * 4 + lg) ^ (r & 7)) << 4);
  }
#pragma unroll
  for (int nf = 0; nf < 2; ++nf) {
    int r = wn * 32 + nf * 16 + lr;  // 0..127
#pragma unroll
    for (int s = 0; s < 2; ++s)
      offB[nf][s] = r * 128 + (((s * 4 + lg) ^ (r & 7)) << 4);
  }

  // staging constants: 2 gload_lds per thread per half-tile, linear LDS dest,
  // inverse-swizzled global k offset
  const int srow = tid >> 3;                       // 0..63
  const int ksrc = ((tid & 7) ^ (srow & 7)) * 8;   // pre-swizzled k elem
  const size_t aRow = (size_t)(m0 + srow) * K_DIM + ksrc;
  const size_t bRow = (size_t)(n0 + srow) * K_DIM + ksrc;
  const int dst0 = tid * 16;

  f32x4 acc[8][4];
#pragma unroll
  for (int i = 0; i < 8; ++i)
#pragma unroll
    for (int j = 0; j < 4; ++j) acc[i][j] = (f32x4){0.f, 0.f, 0.f, 0.f};

  short8 aF[4][2];      // A frags for current mh (reloaded at mh change)
  short8 bF[2][2][2];   // B frags [nh][nf][s], resident for whole K-tile

#define STAGE_A(kt, h)                                                         \
  do {                                                                         \
    size_t g_ = aRow + (size_t)((h) * 128) * K_DIM + (size_t)(kt) * 64;        \
    int d_ = ((((kt) & 1) * 2 + (h)) << 14) + dst0;                            \
    gload_lds16(Xb + g_, lds + d_);                                            \
    gload_lds16(Xb + g_ + (size_t)64 * K_DIM, lds + d_ + 8192);                \
  } while (0)

#define STAGE_B(kt, h)                                                         \
  do {                                                                         \
    size_t g_ = bRow + (size_t)((h) * 128) * K_DIM + (size_t)(kt) * 64;        \
    int d_ = 65536 + ((((kt) & 1) * 2 + (h)) << 14) + dst0;                    \
    gload_lds16(Wb + g_, lds + d_);                                            \
    gload_lds16(Wb + g_ + (size_t)64 * K_DIM, lds + d_ + 8192);                \
  } while (0)

#define FENCE asm volatile("" ::: "memory")

  // PHASE: optional A/B fragment loads, stage stmt, counted-wait stmt,
  // ONE barrier, MFMA cluster under setprio. (No trailing barrier.)
#define PHASE(kt, mh, nh, LA, LB, STMT, WMT)                                   \
  do {                                                                         \
    if (LA) {                                                                  \
      const char* Ab_ = lds + ((((kt) & 1) * 2 + (mh)) << 14);                 \
      _Pragma("unroll") for (int mf = 0; mf < 4; ++mf)                         \
          _Pragma("unroll") for (int s = 0; s < 2; ++s)                        \
              aF[mf][s] = *(const short8*)(Ab_ + offA[mf][s]);                 \
    }                                                                          \
    if (LB) {                                                                  \
      const char* Bb_ = lds + 65536 + ((((kt) & 1) * 2 + (nh)) << 14);         \
      _Pragma("unroll") for (int nf = 0; nf < 2; ++nf)                         \
          _Pragma("unroll") for (int s = 0; s < 2; ++s)                        \
              bF[nh][nf][s] = *(const short8*)(Bb_ + offB[nf][s]);             \
    }                                                                          \
    STMT;                                                                      \
    FENCE;                                                                     \
    WMT;                                                                       \
    __builtin_amdgcn_s_barrier();                                              \
    FENCE;                                                                     \
    __builtin_amdgcn_s_setprio(1);                                             \
    _Pragma("unroll") for (int mf = 0; mf < 4; ++mf)                           \
        _Pragma("unroll") for (int nf = 0; nf < 2; ++nf)                       \
            _Pragma("unroll") for (int s = 0; s < 2; ++s)                      \
                acc[(mh) * 4 + mf][(nh) * 2 + nf] =                            \
                    __builtin_amdgcn_mfma_f32_16x16x32_bf16(                   \
                        aF[mf][s], bF[nh][nf][s],                              \
                        acc[(mh) * 4 + mf][(nh) * 2 + nf], 0, 0, 0);           \
    __builtin_amdgcn_s_setprio(0);                                             \
    FENCE;                                                                     \
  } while (0)

  // ---- prologue: stage kt0 fully + kt1 halves A0,B0; wait kt0 landed ----
  STAGE_A(0, 0); STAGE_B(0, 0); STAGE_A(0, 1); STAGE_B(0, 1);
  STAGE_A(1, 0); STAGE_B(1, 0);
  FENCE;
  asm volatile("s_waitcnt vmcnt(4)" ::: "memory");
  __builtin_amdgcn_s_barrier();
  FENCE;

  // ---- main loop: 112 iterations x 2 K-tiles (K/64 = 224) ----
  for (int i = 0; i < 112; ++i) {
    const int t = 2 * i;
    const bool st = (i < 111);
    PHASE(t, 0, 0, 1, 1, { STAGE_A(t + 1, 1); }, {});
    PHASE(t, 0, 1, 0, 1, { STAGE_B(t + 1, 1); }, {});
    PHASE(t, 1, 0, 1, 0, { if (st) STAGE_A(t + 2, 0); }, {});
    PHASE(t, 1, 1, 0, 0, { if (st) STAGE_B(t + 2, 0); },
          {
            if (st) asm volatile("s_waitcnt vmcnt(4)" ::: "memory");
            else    asm volatile("s_waitcnt vmcnt(0)" ::: "memory");
          });
    PHASE(t + 1, 0, 0, 1, 1, { if (st) STAGE_A(t + 2, 1); }, {});
    PHASE(t + 1, 0, 1, 0, 1, { if (st) STAGE_B(t + 2, 1); }, {});
    PHASE(t + 1, 1, 0, 1, 0, { if (st) STAGE_A(t + 3, 0); }, {});
    PHASE(t + 1, 1, 1, 0, 0, { if (st) STAGE_B(t + 3, 0); },
          {
            if (st) asm volatile("s_waitcnt vmcnt(4)" ::: "memory");
            else    asm volatile("s_waitcnt vmcnt(0)" ::: "memory");
          });
  }

  // ---- epilogue: y = acc*qxscale[m] + residual + bias[n] ----
#pragma unroll
  for (int mh = 0; mh < 2; ++mh)
#pragma unroll
    for (int mf = 0; mf < 4; ++mf)
#pragma unroll
      for (int nh = 0; nh < 2; ++nh)
#pragma unroll
        for (int nf = 0; nf < 2; ++nf) {
          int n = n0 + wn * 32 + nh * 128 + nf * 16 + lr;
          float bv = bias[n];
          f32x4 v = acc[mh * 4 + mf][nh * 2 + nf];
#pragma unroll
          for (int rr = 0; rr < 4; ++rr) {
            int m = m0 + wm * 64 + mh * 128 + mf * 16 + lg * 4 + rr;
            size_t off = (size_t)m * N_DIM + n;
            out[off] = v[rr] * qxscale[m] + residual[off] + bv;
          }
        }
#undef PHASE
#undef STAGE_A
#undef STAGE_B
#undef FENCE
}

// ---------------- fallback GEMM (tiers 2/3): 128x128, 2-barrier ----------------
template <int AMODE, int BMODE>
__global__ __launch_bounds__(256) void dp_gemm(
    const float* __restrict__ qx, const short* __restrict__ Xb,
    const int* __restrict__ Wq, const float* __restrict__ Wsc,
    const short* __restrict__ Wb, const float* __restrict__ qxscale,
    const float* __restrict__ residual, const float* __restrict__ bias,
    float* __restrict__ out) {
  __shared__ short As[128 * 64];
  __shared__ short Bs[128 * 64];

  const int tid = threadIdx.x;
  const int lane = tid & 63;
  const int w = tid >> 6;

  const int nwg = gridDim.x;
  const int cpx = nwg >> 3;
  const int wg = blockIdx.x;
  const int swz = (wg & 7) * cpx + (wg >> 3);
  const int bm = swz / (N_DIM / 128);
  const int bn = swz % (N_DIM / 128);
  const int m0 = bm * 128, n0 = bn * 128;

  const int wm = w >> 1, wn = w & 1;
  const int lr = lane & 15, lg = lane >> 4;

  f32x4 acc[4][4];
#pragma unroll
  for (int i = 0; i < 4; ++i)
#pragma unroll
    for (int j = 0; j < 4; ++j) acc[i][j] = (f32x4){0.f, 0.f, 0.f, 0.f};

  for (int kt = 0; kt < K_DIM / 64; ++kt) {
    const int k0 = kt * 64;
#pragma unroll
    for (int i = 0; i < 4; ++i) {
      int ldsb = i * 4096 + tid * 16;
      int row = ldsb >> 7;
      int slog = ((ldsb >> 4) & 7) ^ (row & 7);
      const float4* p = (const float4*)(qx + (size_t)(m0 + row) * K_DIM + k0 + slog * 8);
      float4 u0 = p[0], u1 = p[1];
      short8 v;
      v[0] = f2bf(u0.x); v[1] = f2bf(u0.y); v[2] = f2bf(u0.z); v[3] = f2bf(u0.w);
      v[4] = f2bf(u1.x); v[5] = f2bf(u1.y); v[6] = f2bf(u1.z); v[7] = f2bf(u1.w);
      *(short8*)((char*)As + ldsb) = v;
    }
    if (BMODE == 0) {
#pragma unroll
      for (int i = 0; i < 4; ++i) {
        int ldsb = i * 4096 + w * 1024 + lane * 16;
        int row = ldsb >> 7;
        int slog = ((ldsb >> 4) & 7) ^ (row & 7);
        gload_lds16(Wb + (size_t)(n0 + row) * K_DIM + k0 + slog * 8, (char*)Bs + ldsb);
      }
    } else {
      int row = tid >> 1;
      int kb = (tid & 1) * 32;
      int4 pw = *(const int4*)(Wq + (size_t)(n0 + row) * (K_DIM / 8) + (k0 + kb) / 8);
      float sc = Wsc[(size_t)(n0 + row) * (K_DIM / GROUP_SZ) + (k0 + kb) / GROUP_SZ];
      int pv[4] = {pw.x, pw.y, pw.z, pw.w};
#pragma unroll
      for (int p = 0; p < 4; ++p) {
        short8 v;
#pragma unroll
        for (int j = 0; j < 8; ++j) {
          int q = (pv[p] << (28 - 4 * j)) >> 28;
          v[j] = f2bf((float)q * sc);
        }
        int slog = (tid & 1) * 4 + p;
        int sp = slog ^ (row & 7);
        *(short8*)((char*)Bs + row * 128 + sp * 16) = v;
      }
    }
    __syncthreads();
#pragma unroll
    for (int s = 0; s < 2; ++s) {
      short8 a[4], b[4];
#pragma unroll
      for (int f = 0; f < 4; ++f) {
        int row = wm * 64 + f * 16 + lr;
        int sp = (s * 4 + lg) ^ (row & 7);
        a[f] = *(const short8*)((char*)As + row * 128 + sp * 16);
      }
#pragma unroll
      for (int f = 0; f < 4; ++f) {
        int row = wn * 64 + f * 16 + lr;
        int sp = (s * 4 + lg) ^ (row & 7);
        b[f] = *(const short8*)((char*)Bs + row * 128 + sp * 16);
      }
#pragma unroll
      for (int i = 0; i < 4; ++i)
#pragma unroll
        for (int j = 0; j < 4; ++j)
          acc[i][j] = __builtin_amdgcn_mfma_f32_16x16x32_bf16(a[i], b[j], acc[i][j], 0, 0, 0);
    }
    __syncthreads();
  }

  const int mb = m0 + wm * 64, nb = n0 + wn * 64;
#pragma unroll
  for (int i = 0; i < 4; ++i)
#pragma unroll
    for (int j = 0; j < 4; ++j) {
      int n = nb + j * 16 + lr;
      float bv = bias[n];
#pragma unroll
      for (int r = 0; r < 4; ++r) {
        int m = mb + i * 16 + lg * 4 + r;
        size_t off = (size_t)m * N_DIM + n;
        out[off] = acc[i][j][r] * qxscale[m] + residual[off] + bv;
      }
    }
}

extern "C" void kernel_launch(void* const* d_in, const int* in_sizes, int n_in,
                              void* d_out, int out_size, void* d_ws, size_t ws_size,
                              hipStream_t stream) {
  const float* qx = (const float*)d_in[0];
  const float* qxscale = (const float*)d_in[1];
  const float* residual = (const float*)d_in[2];
  const int* wq = (const int*)d_in[3];
  const float* wsc = (const float*)d_in[4];
  const float* bias = (const float*)d_in[5];
  float* out = (float*)d_out;

  const size_t need_w = (size_t)N_DIM * K_DIM * 2;
  const size_t need_x = (size_t)M_DIM * K_DIM * 2;
  short* wb = (short*)d_ws;
  short* xb = (short*)((char*)d_ws + need_w);

  if (ws_size >= need_w + need_x) {
    dp_dequant_w<<<dim3(K_DIM / 8 / 256, N_DIM), dim3(256), 0, stream>>>(wq, wsc, wb);
    dp_convert_x<<<dim3(2048), dim3(256), 0, stream>>>(qx, xb,
                                                       (int)((size_t)M_DIM * K_DIM / 8));
    dp_gemm8<<<dim3((M_DIM / 256) * (N_DIM / 256)), dim3(512), 0, stream>>>(
        xb, wb, qxscale, residual, bias, out);
  } else if (ws_size >= need_w) {
    dp_dequant_w<<<dim3(K_DIM / 8 / 256, N_DIM), dim3(256), 0, stream>>>(wq, wsc, wb);
    dp_gemm<1, 0><<<dim3(2048), dim3(256), 0, stream>>>(qx, nullptr, wq, wsc, wb,
                                                        qxscale, residual, bias, out);
  } else {
    dp_gemm<1, 1><<<dim3(2048), dim3(256), 0, stream>>>(qx, nullptr, wq, wsc, nullptr,
                                                        qxscale, residual, bias, out);
  }
}